// Round 1
// baseline (308.859 us; speedup 1.0000x reference)
//
#include <hip/hip_runtime.h>
#include <hip/hip_bf16.h>
#include <stdint.h>

#define D_IN 1024
#define D_K  128
#define NBATCH 8
#define SEQ  4096
#define MROWS (NBATCH * SEQ)

typedef __attribute__((ext_vector_type(8))) short bf16x8;
typedef __attribute__((ext_vector_type(4))) float f32x4;

__device__ __forceinline__ unsigned short f32_to_bf16(float x) {
    union { float f; uint32_t u; } v; v.f = x;
    uint32_t r = 0x7FFFu + ((v.u >> 16) & 1u);
    return (unsigned short)((v.u + r) >> 16);
}

// ---------------- projection GEMM: Y = X * W^T ----------------
// X: [32768][1024] fp32, W: [128][1024] fp32.
// p=0 -> qh row-major bf16 (scaled by log2e/sqrt(128))
// p=1 -> kh row-major bf16
// p=2 -> vhT transposed [b][128][4096] bf16
#define PBM 128
#define PBK 64

__global__ __launch_bounds__(256)
void proj_kernel(const float* __restrict__ Xq, const float* __restrict__ Xk,
                 const float* __restrict__ Xv,
                 const float* __restrict__ Wq, const float* __restrict__ Wk,
                 const float* __restrict__ Wv,
                 unsigned short* __restrict__ qh, unsigned short* __restrict__ kh,
                 unsigned short* __restrict__ vhT)
{
    const int p = blockIdx.y;
    const float* __restrict__ X = (p == 0) ? Xq : (p == 1) ? Xk : Xv;
    const float* __restrict__ W = (p == 0) ? Wq : (p == 1) ? Wk : Wv;

    __shared__ unsigned short As[PBM * PBK];   // [128][64] bf16, XOR-swizzled
    __shared__ unsigned short Bs[D_K * PBK];   // [128][64] bf16, XOR-swizzled

    const int tid  = threadIdx.x;
    const int lane = tid & 63;
    const int wave = tid >> 6;
    const int wr   = (wave >> 1) * 64;   // wave m-offset
    const int wc   = (wave & 1) * 64;    // wave n-offset
    const int m0   = blockIdx.x * PBM;
    const int lrow = lane & 15;
    const int lk16 = (lane >> 4) * 16;   // byte offset of lane's k-slot

    f32x4 acc[4][4];
    #pragma unroll
    for (int i = 0; i < 4; ++i)
        #pragma unroll
        for (int j = 0; j < 4; ++j)
            acc[i][j] = (f32x4){0.f, 0.f, 0.f, 0.f};

    for (int k0 = 0; k0 < D_IN; k0 += PBK) {
        if (k0) __syncthreads();
        // stage A tile: 128 rows x 64 k fp32 -> bf16 LDS (2048 float4 / 256 thr = 8 each)
        #pragma unroll
        for (int i = 0; i < 8; ++i) {
            int slot = i * 256 + tid;
            int row  = slot >> 4;
            int cb   = (slot & 15) * 16;   // byte col within fp32 row-slice (256B)
            float4 a = *reinterpret_cast<const float4*>(
                reinterpret_cast<const char*>(X + (size_t)(m0 + row) * D_IN + k0) + cb);
            uint2 t;
            t.x = (uint32_t)f32_to_bf16(a.x) | ((uint32_t)f32_to_bf16(a.y) << 16);
            t.y = (uint32_t)f32_to_bf16(a.z) | ((uint32_t)f32_to_bf16(a.w) << 16);
            *reinterpret_cast<uint2*>(reinterpret_cast<char*>(As) +
                row * 128 + ((cb >> 1) ^ ((row & 7) << 4))) = t;
        }
        // stage B tile: W rows 0..127 x 64 k
        #pragma unroll
        for (int i = 0; i < 8; ++i) {
            int slot = i * 256 + tid;
            int row  = slot >> 4;
            int cb   = (slot & 15) * 16;
            float4 a = *reinterpret_cast<const float4*>(
                reinterpret_cast<const char*>(W + (size_t)row * D_IN + k0) + cb);
            uint2 t;
            t.x = (uint32_t)f32_to_bf16(a.x) | ((uint32_t)f32_to_bf16(a.y) << 16);
            t.y = (uint32_t)f32_to_bf16(a.z) | ((uint32_t)f32_to_bf16(a.w) << 16);
            *reinterpret_cast<uint2*>(reinterpret_cast<char*>(Bs) +
                row * 128 + ((cb >> 1) ^ ((row & 7) << 4))) = t;
        }
        __syncthreads();

        #pragma unroll
        for (int ks = 0; ks < 2; ++ks) {
            bf16x8 af[4], bfr[4];
            #pragma unroll
            for (int mi = 0; mi < 4; ++mi) {
                int row = wr + mi * 16 + lrow;
                af[mi] = *reinterpret_cast<const bf16x8*>(
                    reinterpret_cast<const char*>(As) + row * 128 +
                    ((ks * 64 + lk16) ^ ((row & 7) << 4)));
            }
            #pragma unroll
            for (int ni = 0; ni < 4; ++ni) {
                int row = wc + ni * 16 + lrow;
                bfr[ni] = *reinterpret_cast<const bf16x8*>(
                    reinterpret_cast<const char*>(Bs) + row * 128 +
                    ((ks * 64 + lk16) ^ ((row & 7) << 4)));
            }
            #pragma unroll
            for (int mi = 0; mi < 4; ++mi)
                #pragma unroll
                for (int ni = 0; ni < 4; ++ni)
                    acc[mi][ni] = __builtin_amdgcn_mfma_f32_16x16x32_bf16(
                        af[mi], bfr[ni], acc[mi][ni], 0, 0, 0);
        }
    }

    const float qscale = 1.44269504088896f * 0.0883883476483184f; // log2e / sqrt(128)
    if (p < 2) {
        unsigned short* __restrict__ Y = (p == 0) ? qh : kh;
        const float scale = (p == 0) ? qscale : 1.0f;
        #pragma unroll
        for (int mi = 0; mi < 4; ++mi) {
            const int mbase = m0 + wr + mi * 16 + ((lane >> 4) << 2);
            #pragma unroll
            for (int ni = 0; ni < 4; ++ni) {
                const int n = wc + ni * 16 + lrow;
                #pragma unroll
                for (int r = 0; r < 4; ++r)
                    Y[(size_t)(mbase + r) * D_K + n] = f32_to_bf16(acc[mi][ni][r] * scale);
            }
        }
    } else {
        const int b  = m0 >> 12;
        const int sb = (m0 & 4095) + wr;
        #pragma unroll
        for (int mi = 0; mi < 4; ++mi) {
            const int s = sb + mi * 16 + ((lane >> 4) << 2);
            #pragma unroll
            for (int ni = 0; ni < 4; ++ni) {
                const int d = wc + ni * 16 + lrow;
                uint2 t;
                t.x = (uint32_t)f32_to_bf16(acc[mi][ni][0]) |
                      ((uint32_t)f32_to_bf16(acc[mi][ni][1]) << 16);
                t.y = (uint32_t)f32_to_bf16(acc[mi][ni][2]) |
                      ((uint32_t)f32_to_bf16(acc[mi][ni][3]) << 16);
                *reinterpret_cast<uint2*>(vhT + ((size_t)(b * D_K + d) << 12) + s) = t;
            }
        }
    }
}

// ---------------- flash attention (no-max-subtract streaming softmax) ----------------
#define KVB 64

__global__ __launch_bounds__(256)
void attn_kernel(const unsigned short* __restrict__ qh,
                 const unsigned short* __restrict__ kh,
                 const unsigned short* __restrict__ vhT,
                 float* __restrict__ out)
{
    __shared__ unsigned short Ks[KVB * D_K];    // [64][128] swizzled
    __shared__ unsigned short Vs[D_K * KVB];    // [128][64] swizzled (V^T)
    __shared__ unsigned short Ps[4][32 * KVB];  // per-wave [32][64] swizzled

    const int tid  = threadIdx.x;
    const int lane = tid & 63;
    const int wave = tid >> 6;
    const int b    = blockIdx.x & 7;    // batch -> XCD for L2 locality
    const int qt   = blockIdx.x >> 3;
    const int q0   = qt * 128 + wave * 32;
    const int lrow = lane & 15;
    const int lk16 = (lane >> 4) * 16;

    // hoist Q fragments (already scaled by log2e/sqrt(128))
    bf16x8 qf[2][4];
    #pragma unroll
    for (int mi = 0; mi < 2; ++mi) {
        const char* base = reinterpret_cast<const char*>(
            qh + (size_t)(b * SEQ + q0 + mi * 16 + lrow) * D_K);
        #pragma unroll
        for (int ks = 0; ks < 4; ++ks)
            qf[mi][ks] = *reinterpret_cast<const bf16x8*>(base + ks * 64 + lk16);
    }

    f32x4 o[2][8];
    #pragma unroll
    for (int mi = 0; mi < 2; ++mi)
        #pragma unroll
        for (int df = 0; df < 8; ++df)
            o[mi][df] = (f32x4){0.f, 0.f, 0.f, 0.f};
    float lsum[2][4];
    #pragma unroll
    for (int mi = 0; mi < 2; ++mi)
        #pragma unroll
        for (int r = 0; r < 4; ++r) lsum[mi][r] = 0.f;

    const unsigned short* __restrict__ Kb = kh + (size_t)b * SEQ * D_K;
    const unsigned short* __restrict__ Vb = vhT + (size_t)b * D_K * SEQ;
    unsigned short* const Pw = Ps[wave];

    for (int s0 = 0; s0 < SEQ; s0 += KVB) {
        __syncthreads();
        // stage K tile [64][128]
        #pragma unroll
        for (int i = 0; i < 4; ++i) {
            int slot = i * 256 + tid;
            int row  = slot >> 4;
            int cb   = (slot & 15) * 16;
            uint4 t = *reinterpret_cast<const uint4*>(
                reinterpret_cast<const char*>(Kb + (size_t)(s0 + row) * D_K) + cb);
            *reinterpret_cast<uint4*>(reinterpret_cast<char*>(Ks) +
                row * 256 + (cb ^ ((row & 7) << 4))) = t;
        }
        // stage V^T tile [128][64]
        #pragma unroll
        for (int i = 0; i < 4; ++i) {
            int slot = i * 256 + tid;
            int row  = slot >> 3;
            int cb   = (slot & 7) * 16;
            uint4 t = *reinterpret_cast<const uint4*>(
                reinterpret_cast<const char*>(Vb + (size_t)row * SEQ + s0) + cb);
            *reinterpret_cast<uint4*>(reinterpret_cast<char*>(Vs) +
                row * 128 + (cb ^ ((row & 7) << 4))) = t;
        }
        __syncthreads();

        // QK^T: sc[mi][sf] = Q(32 x 128) . K(64 x 128)^T
        f32x4 sc[2][4];
        #pragma unroll
        for (int mi = 0; mi < 2; ++mi)
            #pragma unroll
            for (int sf = 0; sf < 4; ++sf)
                sc[mi][sf] = (f32x4){0.f, 0.f, 0.f, 0.f};

        #pragma unroll
        for (int ks = 0; ks < 4; ++ks) {
            bf16x8 kf[4];
            #pragma unroll
            for (int sf = 0; sf < 4; ++sf) {
                int row = sf * 16 + lrow;
                kf[sf] = *reinterpret_cast<const bf16x8*>(
                    reinterpret_cast<const char*>(Ks) + row * 256 +
                    ((ks * 64 + lk16) ^ ((row & 7) << 4)));
            }
            #pragma unroll
            for (int mi = 0; mi < 2; ++mi)
                #pragma unroll
                for (int sf = 0; sf < 4; ++sf)
                    sc[mi][sf] = __builtin_amdgcn_mfma_f32_16x16x32_bf16(
                        qf[mi][ks], kf[sf], sc[mi][sf], 0, 0, 0);
        }

        // p = exp2(s'); accumulate row-sums per-lane; spill P (bf16) to LDS
        #pragma unroll
        for (int mi = 0; mi < 2; ++mi) {
            #pragma unroll
            for (int sf = 0; sf < 4; ++sf) {
                #pragma unroll
                for (int r = 0; r < 4; ++r) {
                    float pv = exp2f(sc[mi][sf][r]);
                    lsum[mi][r] += pv;
                    int prow = mi * 16 + ((lane >> 4) << 2) + r;
                    int pcol = (sf * 16 + lrow) * 2;
                    *reinterpret_cast<unsigned short*>(
                        reinterpret_cast<char*>(Pw) + prow * 128 +
                        (pcol ^ ((prow & 7) << 4))) = f32_to_bf16(pv);
                }
            }
        }

        // PV: o[mi][df] += P(32 x 64) . V(64 x 128)
        #pragma unroll
        for (int ks = 0; ks < 2; ++ks) {
            bf16x8 pf[2];
            #pragma unroll
            for (int mi = 0; mi < 2; ++mi) {
                int row = mi * 16 + lrow;
                pf[mi] = *reinterpret_cast<const bf16x8*>(
                    reinterpret_cast<const char*>(Pw) + row * 128 +
                    ((ks * 64 + lk16) ^ ((row & 7) << 4)));
            }
            #pragma unroll
            for (int df = 0; df < 8; ++df) {
                int vrow = df * 16 + lrow;
                bf16x8 vf = *reinterpret_cast<const bf16x8*>(
                    reinterpret_cast<const char*>(Vs) + vrow * 128 +
                    ((ks * 64 + lk16) ^ ((vrow & 7) << 4)));
                #pragma unroll
                for (int mi = 0; mi < 2; ++mi)
                    o[mi][df] = __builtin_amdgcn_mfma_f32_16x16x32_bf16(
                        pf[mi], vf, o[mi][df], 0, 0, 0);
            }
        }
    }

    // finalize: reduce row-sums across the 16-lane group, divide, store fp32
    #pragma unroll
    for (int mi = 0; mi < 2; ++mi) {
        #pragma unroll
        for (int r = 0; r < 4; ++r) {
            float s = lsum[mi][r];
            s += __shfl_xor(s, 1);
            s += __shfl_xor(s, 2);
            s += __shfl_xor(s, 4);
            s += __shfl_xor(s, 8);
            float inv = 1.0f / s;
            const int row = q0 + mi * 16 + ((lane >> 4) << 2) + r;
            float* ob = out + (size_t)(b * SEQ + row) * D_K + lrow;
            #pragma unroll
            for (int df = 0; df < 8; ++df)
                ob[df * 16] = o[mi][df][r] * inv;
        }
    }
}

extern "C" void kernel_launch(void* const* d_in, const int* in_sizes, int n_in,
                              void* d_out, int out_size, void* d_ws, size_t ws_size,
                              hipStream_t stream)
{
    (void)in_sizes; (void)n_in; (void)out_size; (void)ws_size;
    const float* q  = (const float*)d_in[0];
    const float* k  = (const float*)d_in[1];
    const float* v  = (const float*)d_in[2];
    const float* Wq = (const float*)d_in[3];
    const float* Wk = (const float*)d_in[4];
    const float* Wv = (const float*)d_in[5];

    unsigned short* qh  = (unsigned short*)d_ws;                 // [32768][128] bf16
    unsigned short* kh  = qh + (size_t)MROWS * D_K;              // [32768][128] bf16
    unsigned short* vhT = kh + (size_t)MROWS * D_K;              // [8][128][4096] bf16

    proj_kernel<<<dim3(MROWS / PBM, 3), 256, 0, stream>>>(q, k, v, Wq, Wk, Wv, qh, kh, vhT);
    attn_kernel<<<dim3(NBATCH * (SEQ / 128)), 256, 0, stream>>>(qh, kh, vhT, (float*)d_out);
}

// Round 2
// 274.743 us; speedup vs baseline: 1.1242x; 1.1242x over previous
//
#include <hip/hip_runtime.h>
#include <hip/hip_bf16.h>
#include <stdint.h>

#define D_IN 1024
#define D_K  128
#define NBATCH 8
#define SEQ  4096
#define MROWS (NBATCH * SEQ)

typedef __attribute__((ext_vector_type(8))) short bf16x8;
typedef __attribute__((ext_vector_type(4))) float f32x4;

__device__ __forceinline__ unsigned short f32_to_bf16(float x) {
    union { float f; uint32_t u; } v; v.f = x;
    uint32_t r = 0x7FFFu + ((v.u >> 16) & 1u);
    return (unsigned short)((v.u + r) >> 16);
}

__device__ __forceinline__ bf16x8 cvt8(float4 lo, float4 hi) {
    bf16x8 r;
    r[0] = (short)f32_to_bf16(lo.x); r[1] = (short)f32_to_bf16(lo.y);
    r[2] = (short)f32_to_bf16(lo.z); r[3] = (short)f32_to_bf16(lo.w);
    r[4] = (short)f32_to_bf16(hi.x); r[5] = (short)f32_to_bf16(hi.y);
    r[6] = (short)f32_to_bf16(hi.z); r[7] = (short)f32_to_bf16(hi.w);
    return r;
}

__device__ __forceinline__ void gload16(const void* src, void* lds) {
    __builtin_amdgcn_global_load_lds(
        (const __attribute__((address_space(1))) void*)src,
        (__attribute__((address_space(3))) void*)lds, 16, 0, 0);
}

// ---------------- W pre-convert: fp32 -> bf16, k-chunk-major ----------------
// Wt[p][kc=0..127][n=0..127] = 8 bf16 of W_p[n][kc*8 .. kc*8+8)  (Wq scaled)
__global__ __launch_bounds__(256)
void wconv_kernel(const float* __restrict__ Wq, const float* __restrict__ Wk,
                  const float* __restrict__ Wv, unsigned short* __restrict__ Wt)
{
    const int t  = blockIdx.x * 256 + threadIdx.x;   // 49152 threads
    const int n  = t & 127;
    const int kc = (t >> 7) & 127;
    const int p  = t >> 14;
    const float* __restrict__ W = (p == 0) ? Wq : (p == 1) ? Wk : Wv;
    const float sc = (p == 0) ? (1.44269504088896f * 0.0883883476483184f) : 1.0f;
    const float4* src = reinterpret_cast<const float4*>(W + (size_t)n * D_IN + kc * 8);
    float4 a = src[0], b = src[1];
    uint4 o;
    o.x = (uint32_t)f32_to_bf16(a.x * sc) | ((uint32_t)f32_to_bf16(a.y * sc) << 16);
    o.y = (uint32_t)f32_to_bf16(a.z * sc) | ((uint32_t)f32_to_bf16(a.w * sc) << 16);
    o.z = (uint32_t)f32_to_bf16(b.x * sc) | ((uint32_t)f32_to_bf16(b.y * sc) << 16);
    o.w = (uint32_t)f32_to_bf16(b.z * sc) | ((uint32_t)f32_to_bf16(b.w * sc) << 16);
    *reinterpret_cast<uint4*>(Wt + (size_t)t * 8) = o;
}

// ---------------- projection GEMM: Y = X * W^T ----------------
// A staged fp32 in LDS via global_load_lds (triple buffer, 2-ahead prefetch,
// XOR source-swizzle); B read directly from bf16 Wt (L2-resident).
#define PBM 128
#define PBK 32
#define NT  (D_IN / PBK)   // 32 k-steps

__global__ __launch_bounds__(256)
void proj_kernel(const float* __restrict__ Xq, const float* __restrict__ Xk,
                 const float* __restrict__ Xv,
                 const unsigned short* __restrict__ Wt,
                 unsigned short* __restrict__ qh, unsigned short* __restrict__ kh,
                 unsigned short* __restrict__ vhT)
{
    const int p = blockIdx.y;
    const float* __restrict__ X = (p == 0) ? Xq : (p == 1) ? Xk : Xv;
    const unsigned short* __restrict__ Wtp = Wt + (size_t)p * 128 * 128 * 8;

    __shared__ float As[3 * PBM * PBK];   // 3 x 16KB, chunk-XOR-swizzled

    const int tid  = threadIdx.x;
    const int lane = tid & 63;
    const int wave = tid >> 6;
    const int wr   = (wave >> 1) * 64;
    const int wc   = (wave & 1) * 64;
    const int m0   = blockIdx.x * PBM;
    const int lrow = lane & 15;
    const int g    = lane >> 4;          // k-slot group 0..3
    const int r8   = lane >> 3;          // staging row-within-8
    const int csrc = (lane & 7) ^ r8;    // pre-swizzled source chunk

    const float* __restrict__ Xb = X + (size_t)m0 * D_IN;

    f32x4 acc[4][4];
    #pragma unroll
    for (int i = 0; i < 4; ++i)
        #pragma unroll
        for (int j = 0; j < 4; ++j)
            acc[i][j] = (f32x4){0.f, 0.f, 0.f, 0.f};

    // stage one 128x32 fp32 tile into buffer `buf` (4 gload_lds per wave)
    #define STAGE(buf, t_)                                                    \
    do {                                                                      \
        const int k0_ = (t_) * PBK;                                           \
        _Pragma("unroll")                                                     \
        for (int j = 0; j < 4; ++j) {                                         \
            const int row_ = wave * 32 + j * 8 + r8;                          \
            gload16(Xb + (size_t)row_ * D_IN + k0_ + csrc * 4,                \
                    &As[(buf) * (PBM * PBK) + (wave * 4 + j) * 256]);         \
        }                                                                     \
    } while (0)

    STAGE(0, 0);
    STAGE(1, 1);
    asm volatile("s_waitcnt vmcnt(4)" ::: "memory");   // tile 0 arrived
    __builtin_amdgcn_s_barrier();

    int cur = 0;
    for (int t = 0; t < NT; ++t) {
        // B fragments for tile t: direct bf16 loads (L2-hot Wt)
        bf16x8 bfr[4];
        const size_t kcb = (size_t)(t * 4 + g) * 128;
        #pragma unroll
        for (int ni = 0; ni < 4; ++ni)
            bfr[ni] = *reinterpret_cast<const bf16x8*>(
                Wtp + (kcb + wc + ni * 16 + lrow) * 8);

        // prefetch tile t+2
        if (t + 2 < NT) {
            const int nb = (cur + 2 >= 3) ? cur - 1 : cur + 2;
            STAGE(nb, t + 2);
        }

        // A fragments (fp32 swizzled LDS -> bf16) + MFMA
        const float* Ab = &As[cur * (PBM * PBK)];
        #pragma unroll
        for (int mi = 0; mi < 4; ++mi) {
            const int row = wr + mi * 16 + lrow;
            const float* base = Ab + row * 32;
            float4 lo = *reinterpret_cast<const float4*>(base + (((2 * g)     ^ (row & 7)) * 4));
            float4 hi = *reinterpret_cast<const float4*>(base + (((2 * g + 1) ^ (row & 7)) * 4));
            bf16x8 af = cvt8(lo, hi);
            #pragma unroll
            for (int ni = 0; ni < 4; ++ni)
                acc[mi][ni] = __builtin_amdgcn_mfma_f32_16x16x32_bf16(
                    af, bfr[ni], acc[mi][ni], 0, 0, 0);
        }

        __builtin_amdgcn_s_barrier();  // all waves done reading buf[cur]
        if (t + 2 < NT)
            asm volatile("s_waitcnt vmcnt(4)" ::: "memory");  // tile t+1 arrived
        else
            asm volatile("s_waitcnt vmcnt(0)" ::: "memory");
        __builtin_amdgcn_s_barrier();  // tile t+1 visible to all waves
        cur = (cur == 2) ? 0 : cur + 1;
    }
    #undef STAGE

    if (p < 2) {
        unsigned short* __restrict__ Y = (p == 0) ? qh : kh;
        #pragma unroll
        for (int mi = 0; mi < 4; ++mi) {
            const int mbase = m0 + wr + mi * 16 + ((lane >> 4) << 2);
            #pragma unroll
            for (int ni = 0; ni < 4; ++ni) {
                const int n = wc + ni * 16 + lrow;
                #pragma unroll
                for (int r = 0; r < 4; ++r)
                    Y[(size_t)(mbase + r) * D_K + n] = f32_to_bf16(acc[mi][ni][r]);
            }
        }
    } else {
        const int b  = m0 >> 12;
        const int sb = (m0 & 4095) + wr;
        #pragma unroll
        for (int mi = 0; mi < 4; ++mi) {
            const int s = sb + mi * 16 + ((lane >> 4) << 2);
            #pragma unroll
            for (int ni = 0; ni < 4; ++ni) {
                const int d = wc + ni * 16 + lrow;
                uint2 t;
                t.x = (uint32_t)f32_to_bf16(acc[mi][ni][0]) |
                      ((uint32_t)f32_to_bf16(acc[mi][ni][1]) << 16);
                t.y = (uint32_t)f32_to_bf16(acc[mi][ni][2]) |
                      ((uint32_t)f32_to_bf16(acc[mi][ni][3]) << 16);
                *reinterpret_cast<uint2*>(vhT + ((size_t)(b * D_K + d) << 12) + s) = t;
            }
        }
    }
}

// ---------------- flash attention (no-max-subtract streaming softmax) ----------------
#define KVB 64

__global__ __launch_bounds__(256)
void attn_kernel(const unsigned short* __restrict__ qh,
                 const unsigned short* __restrict__ kh,
                 const unsigned short* __restrict__ vhT,
                 float* __restrict__ out)
{
    __shared__ unsigned short Ks[KVB * D_K];    // [64][128] swizzled
    __shared__ unsigned short Vs[D_K * KVB];    // [128][64] swizzled (V^T)
    __shared__ unsigned short Ps[4][32 * KVB];  // per-wave [32][64] swizzled

    const int tid  = threadIdx.x;
    const int lane = tid & 63;
    const int wave = tid >> 6;
    const int b    = blockIdx.x & 7;    // batch -> XCD for L2 locality
    const int qt   = blockIdx.x >> 3;
    const int q0   = qt * 128 + wave * 32;
    const int lrow = lane & 15;
    const int lk16 = (lane >> 4) * 16;

    bf16x8 qf[2][4];
    #pragma unroll
    for (int mi = 0; mi < 2; ++mi) {
        const char* base = reinterpret_cast<const char*>(
            qh + (size_t)(b * SEQ + q0 + mi * 16 + lrow) * D_K);
        #pragma unroll
        for (int ks = 0; ks < 4; ++ks)
            qf[mi][ks] = *reinterpret_cast<const bf16x8*>(base + ks * 64 + lk16);
    }

    f32x4 o[2][8];
    #pragma unroll
    for (int mi = 0; mi < 2; ++mi)
        #pragma unroll
        for (int df = 0; df < 8; ++df)
            o[mi][df] = (f32x4){0.f, 0.f, 0.f, 0.f};
    float lsum[2][4];
    #pragma unroll
    for (int mi = 0; mi < 2; ++mi)
        #pragma unroll
        for (int r = 0; r < 4; ++r) lsum[mi][r] = 0.f;

    const unsigned short* __restrict__ Kb = kh + (size_t)b * SEQ * D_K;
    const unsigned short* __restrict__ Vb = vhT + (size_t)b * D_K * SEQ;
    unsigned short* const Pw = Ps[wave];

    for (int s0 = 0; s0 < SEQ; s0 += KVB) {
        __syncthreads();
        #pragma unroll
        for (int i = 0; i < 4; ++i) {
            int slot = i * 256 + tid;
            int row  = slot >> 4;
            int cb   = (slot & 15) * 16;
            uint4 t = *reinterpret_cast<const uint4*>(
                reinterpret_cast<const char*>(Kb + (size_t)(s0 + row) * D_K) + cb);
            *reinterpret_cast<uint4*>(reinterpret_cast<char*>(Ks) +
                row * 256 + (cb ^ ((row & 7) << 4))) = t;
        }
        #pragma unroll
        for (int i = 0; i < 4; ++i) {
            int slot = i * 256 + tid;
            int row  = slot >> 3;
            int cb   = (slot & 7) * 16;
            uint4 t = *reinterpret_cast<const uint4*>(
                reinterpret_cast<const char*>(Vb + (size_t)row * SEQ + s0) + cb);
            *reinterpret_cast<uint4*>(reinterpret_cast<char*>(Vs) +
                row * 128 + (cb ^ ((row & 7) << 4))) = t;
        }
        __syncthreads();

        f32x4 sc[2][4];
        #pragma unroll
        for (int mi = 0; mi < 2; ++mi)
            #pragma unroll
            for (int sf = 0; sf < 4; ++sf)
                sc[mi][sf] = (f32x4){0.f, 0.f, 0.f, 0.f};

        #pragma unroll
        for (int ks = 0; ks < 4; ++ks) {
            bf16x8 kf[4];
            #pragma unroll
            for (int sf = 0; sf < 4; ++sf) {
                int row = sf * 16 + lrow;
                kf[sf] = *reinterpret_cast<const bf16x8*>(
                    reinterpret_cast<const char*>(Ks) + row * 256 +
                    ((ks * 64 + lk16) ^ ((row & 7) << 4)));
            }
            #pragma unroll
            for (int mi = 0; mi < 2; ++mi)
                #pragma unroll
                for (int sf = 0; sf < 4; ++sf)
                    sc[mi][sf] = __builtin_amdgcn_mfma_f32_16x16x32_bf16(
                        qf[mi][ks], kf[sf], sc[mi][sf], 0, 0, 0);
        }

        #pragma unroll
        for (int mi = 0; mi < 2; ++mi) {
            #pragma unroll
            for (int sf = 0; sf < 4; ++sf) {
                #pragma unroll
                for (int r = 0; r < 4; ++r) {
                    float pv = exp2f(sc[mi][sf][r]);
                    lsum[mi][r] += pv;
                    int prow = mi * 16 + ((lane >> 4) << 2) + r;
                    int pcol = (sf * 16 + lrow) * 2;
                    *reinterpret_cast<unsigned short*>(
                        reinterpret_cast<char*>(Pw) + prow * 128 +
                        (pcol ^ ((prow & 7) << 4))) = f32_to_bf16(pv);
                }
            }
        }

        #pragma unroll
        for (int ks = 0; ks < 2; ++ks) {
            bf16x8 pf[2];
            #pragma unroll
            for (int mi = 0; mi < 2; ++mi) {
                int row = mi * 16 + lrow;
                pf[mi] = *reinterpret_cast<const bf16x8*>(
                    reinterpret_cast<const char*>(Pw) + row * 128 +
                    ((ks * 64 + lk16) ^ ((row & 7) << 4)));
            }
            #pragma unroll
            for (int df = 0; df < 8; ++df) {
                int vrow = df * 16 + lrow;
                bf16x8 vf = *reinterpret_cast<const bf16x8*>(
                    reinterpret_cast<const char*>(Vs) + vrow * 128 +
                    ((ks * 64 + lk16) ^ ((vrow & 7) << 4)));
                #pragma unroll
                for (int mi = 0; mi < 2; ++mi)
                    o[mi][df] = __builtin_amdgcn_mfma_f32_16x16x32_bf16(
                        pf[mi], vf, o[mi][df], 0, 0, 0);
            }
        }
    }

    #pragma unroll
    for (int mi = 0; mi < 2; ++mi) {
        #pragma unroll
        for (int r = 0; r < 4; ++r) {
            float s = lsum[mi][r];
            s += __shfl_xor(s, 1);
            s += __shfl_xor(s, 2);
            s += __shfl_xor(s, 4);
            s += __shfl_xor(s, 8);
            float inv = 1.0f / s;
            const int row = q0 + mi * 16 + ((lane >> 4) << 2) + r;
            float* ob = out + (size_t)(b * SEQ + row) * D_K + lrow;
            #pragma unroll
            for (int df = 0; df < 8; ++df)
                ob[df * 16] = o[mi][df][r] * inv;
        }
    }
}

extern "C" void kernel_launch(void* const* d_in, const int* in_sizes, int n_in,
                              void* d_out, int out_size, void* d_ws, size_t ws_size,
                              hipStream_t stream)
{
    (void)in_sizes; (void)n_in; (void)out_size; (void)ws_size;
    const float* q  = (const float*)d_in[0];
    const float* k  = (const float*)d_in[1];
    const float* v  = (const float*)d_in[2];
    const float* Wq = (const float*)d_in[3];
    const float* Wk = (const float*)d_in[4];
    const float* Wv = (const float*)d_in[5];

    unsigned short* qh  = (unsigned short*)d_ws;                 // [32768][128] bf16
    unsigned short* kh  = qh + (size_t)MROWS * D_K;              // [32768][128] bf16
    unsigned short* vhT = kh + (size_t)MROWS * D_K;              // [8][128][4096] bf16
    unsigned short* Wt  = vhT + (size_t)MROWS * D_K;             // [3][128][128][8] bf16 (768KB)

    wconv_kernel<<<dim3(192), 256, 0, stream>>>(Wq, Wk, Wv, Wt);
    proj_kernel<<<dim3(MROWS / PBM, 3), 256, 0, stream>>>(q, k, v, Wt, qh, kh, vhT);
    attn_kernel<<<dim3(NBATCH * (SEQ / 128)), 256, 0, stream>>>(qh, kh, vhT, (float*)d_out);
}